// Round 1
// baseline (931.504 us; speedup 1.0000x reference)
//
#include <hip/hip_runtime.h>
#include <hip/hip_bf16.h>
#include <stdint.h>

#define NG 128
#define EPSI 1e-5f

typedef __attribute__((ext_vector_type(8))) __bf16 bf16x8;
typedef __attribute__((ext_vector_type(4))) float f32x4;

union ABFrag { bf16x8 v; unsigned short u[8]; uint4 q; };

__device__ __forceinline__ float b2f(unsigned short u){
  union { unsigned int i; float f; } v; v.i = ((unsigned int)u) << 16; return v.f;
}
__device__ __forceinline__ unsigned short f2b(float f){
  union { float f; unsigned int i; } v; v.f = f;
  unsigned int r = v.i + 0x7fffu + ((v.i >> 16) & 1u);
  return (unsigned short)(r >> 16);
}

// ---------------- prep: fp32 -> bf16 conversions ----------------
// Wcat[64][512]: cols 0..255 = W1[k][n] (P part), cols 256..511 = W1[k+64][n] (Q part)
__global__ void kprep(const float* __restrict__ emb, const float* __restrict__ W1,
                      const float* __restrict__ W2,
                      unsigned short* __restrict__ embb, unsigned short* __restrict__ Wcatb,
                      unsigned short* __restrict__ W2b, int N){
  int idx = blockIdx.x * 256 + threadIdx.x;
  int stride = gridDim.x * 256;
  int embCnt = N * 64;
  for (int i = idx; i < embCnt; i += stride) embb[i] = f2b(emb[i]);
  for (int i = idx; i < 64 * 512; i += stride){
    int k = i >> 9, n = i & 511;
    float wv = (n < 256) ? W1[k * 256 + n] : W1[(k + 64) * 256 + (n - 256)];
    Wcatb[i] = f2b(wv);
  }
  for (int i = idx; i < 256 * 64; i += stride) W2b[i] = f2b(W2[i]);
}

// ---------------- sort edges by segment (counting sort) ----------------
__global__ void khist(const int* __restrict__ ei, const int* __restrict__ batch, int E,
                      unsigned int* __restrict__ hist){
  __shared__ unsigned int h[NG];
  for (int i = threadIdx.x; i < NG; i += blockDim.x) h[i] = 0;
  __syncthreads();
  int idx = blockIdx.x * blockDim.x + threadIdx.x;
  for (int e = idx; e < E; e += gridDim.x * blockDim.x)
    atomicAdd(&h[batch[ei[e]]], 1u);
  __syncthreads();
  for (int i = threadIdx.x; i < NG; i += blockDim.x)
    if (h[i]) atomicAdd(&hist[i], h[i]);
}

__global__ void kscan(const unsigned int* __restrict__ hist, unsigned int* __restrict__ cursor){
  if (threadIdx.x == 0 && blockIdx.x == 0){
    unsigned int s = 0;
    for (int g = 0; g < NG; ++g){ cursor[g] = s; s += hist[g]; }
  }
}

__global__ void kscatter(const int* __restrict__ ei, const int* __restrict__ batch, int E,
                         unsigned int* __restrict__ cursor, int* __restrict__ eord,
                         int* __restrict__ sseg){
  __shared__ unsigned int lc[NG];
  __shared__ unsigned int base[NG];
  for (int i = threadIdx.x; i < NG; i += 256) lc[i] = 0;
  __syncthreads();
  int e0 = blockIdx.x * 1024;
  unsigned int r[4]; int gg[4]; int ee[4];
  #pragma unroll
  for (int j = 0; j < 4; ++j){
    int e = e0 + j * 256 + threadIdx.x;
    ee[j] = e;
    if (e < E){ int g = batch[ei[e]]; gg[j] = g; r[j] = atomicAdd(&lc[g], 1u); }
  }
  __syncthreads();
  for (int i = threadIdx.x; i < NG; i += 256){
    unsigned int c = lc[i];
    base[i] = c ? atomicAdd(&cursor[i], c) : 0u;
  }
  __syncthreads();
  #pragma unroll
  for (int j = 0; j < 4; ++j){
    if (ee[j] < E){
      unsigned int p = base[gg[j]] + r[j];
      eord[p] = ee[j]; sseg[p] = gg[j];
    }
  }
}

// ---------------- GEMM1: PQ[N,512] = embb[N,64] @ Wcat[64,512] (+b1 on P cols) ----------------
__global__ void __launch_bounds__(256) kgemm1(const unsigned short* __restrict__ embb,
    const unsigned short* __restrict__ Wcatb, const float* __restrict__ b1,
    unsigned short* __restrict__ PQb, int Nn){
  int wave = threadIdx.x >> 6, lane = threadIdx.x & 63;
  int quad = lane >> 4, l15 = lane & 15;
  int t = blockIdx.x * 4 + wave;
  int tmmax = (Nn + 15) >> 4;
  int tm = t >> 5, tn = t & 31;
  if (tm >= tmmax) return;
  int m = tm * 16 + l15; if (m >= Nn) m = Nn - 1;
  f32x4 acc = {0.f, 0.f, 0.f, 0.f};
  #pragma unroll
  for (int ks = 0; ks < 2; ++ks){
    int k0 = ks * 32 + quad * 8;
    ABFrag a, b;
    a.q = *(const uint4*)(embb + (size_t)m * 64 + k0);
    int n = tn * 16 + l15;
    #pragma unroll
    for (int j = 0; j < 8; ++j) b.u[j] = Wcatb[(k0 + j) * 512 + n];
    acc = __builtin_amdgcn_mfma_f32_16x16x32_bf16(a.v, b.v, acc, 0, 0, 0);
  }
  int col = tn * 16 + l15;
  float bias = (col < 256) ? b1[col] : 0.0f;
  #pragma unroll
  for (int r = 0; r < 4; ++r){
    int rowg = tm * 16 + quad * 4 + r;
    if (rowg < Nn) PQb[(size_t)rowg * 512 + col] = f2b(acc[r] + bias);
  }
}

// ---------------- stats over y1 = P[col]+Q[row] (sorted edges, register accum) ----------------
__global__ void kstats1(const unsigned short* __restrict__ PQb, const int* __restrict__ ei,
                        const int* __restrict__ eord, const int* __restrict__ sseg, int E,
                        float* __restrict__ sum1, float* __restrict__ sq1){
  int wave = threadIdx.x >> 6, lane = threadIdx.x & 63;
  int per = (E + gridDim.x - 1) / gridDim.x;
  int i0 = blockIdx.x * per;
  int i1 = min(E, i0 + per);
  int c = lane * 4;
  float s0=0,s1=0,s2=0,s3=0,q0=0,q1=0,q2=0,q3=0;
  int cur = -1;
  for (int i = i0 + wave; i < i1; i += 4){
    int g = sseg[i];
    if (g != cur){
      if (cur >= 0){
        atomicAdd(&sum1[cur*256+c+0], s0); atomicAdd(&sum1[cur*256+c+1], s1);
        atomicAdd(&sum1[cur*256+c+2], s2); atomicAdd(&sum1[cur*256+c+3], s3);
        atomicAdd(&sq1[cur*256+c+0], q0); atomicAdd(&sq1[cur*256+c+1], q1);
        atomicAdd(&sq1[cur*256+c+2], q2); atomicAdd(&sq1[cur*256+c+3], q3);
        s0=s1=s2=s3=q0=q1=q2=q3=0.f;
      }
      cur = g;
    }
    int e = eord[i];
    int cn = ei[e], rn = ei[E + e];
    ushort4 pu = *(const ushort4*)(PQb + (size_t)cn * 512 + c);
    ushort4 qu = *(const ushort4*)(PQb + (size_t)rn * 512 + 256 + c);
    float y0 = b2f(pu.x) + b2f(qu.x);
    float y1 = b2f(pu.y) + b2f(qu.y);
    float y2 = b2f(pu.z) + b2f(qu.z);
    float y3 = b2f(pu.w) + b2f(qu.w);
    s0 += y0; s1 += y1; s2 += y2; s3 += y3;
    q0 += y0*y0; q1 += y1*y1; q2 += y2*y2; q3 += y3*y3;
  }
  if (cur >= 0){
    atomicAdd(&sum1[cur*256+c+0], s0); atomicAdd(&sum1[cur*256+c+1], s1);
    atomicAdd(&sum1[cur*256+c+2], s2); atomicAdd(&sum1[cur*256+c+3], s3);
    atomicAdd(&sq1[cur*256+c+0], q0); atomicAdd(&sq1[cur*256+c+1], q1);
    atomicAdd(&sq1[cur*256+c+2], q2); atomicAdd(&sq1[cur*256+c+3], q3);
  }
}

__global__ void kfin(const float* __restrict__ sum, const float* __restrict__ sq,
                     const unsigned int* __restrict__ hist,
                     float* __restrict__ meanA, float* __restrict__ rstdA, int C){
  int i = blockIdx.x * blockDim.x + threadIdx.x;
  if (i >= NG * C) return;
  int g = i / C;
  float cnt = fmaxf((float)hist[g], 1.0f);
  float m = sum[i] / cnt;
  float v = sq[i] / cnt - m * m;
  meanA[i] = m;
  rstdA[i] = rsqrtf(fmaxf(v, 0.f) + EPSI);
}

// ---------------- fused: normalize+ReLU layer1 -> GEMM2 -> y2 (pre-norm) ----------------
__global__ void __launch_bounds__(256) kmain(const unsigned short* __restrict__ PQb,
    const unsigned short* __restrict__ W2b, const int* __restrict__ ei,
    const int* __restrict__ eord, const int* __restrict__ sseg,
    const float* __restrict__ mean1, const float* __restrict__ rstd1,
    const float* __restrict__ b2, unsigned short* __restrict__ y2b, int E){
  __shared__ unsigned short tileA[16][264];  // +8 pad: ds_read_b128 at 2-way (free)
  int wave = threadIdx.x >> 6, lane = threadIdx.x & 63;
  int quad = lane >> 4, l15 = lane & 15;
  // Preload W2 B-fragments for this wave's 16-col strip, all 8 k-steps (32 VGPRs)
  ABFrag bk[8];
  #pragma unroll
  for (int ks = 0; ks < 8; ++ks)
    #pragma unroll
    for (int j = 0; j < 8; ++j)
      bk[ks].u[j] = W2b[(ks * 32 + quad * 8 + j) * 64 + wave * 16 + l15];
  float bias2 = b2[wave * 16 + l15];
  int nt = (E + 15) >> 4;
  for (int tb = blockIdx.x; tb < nt; tb += gridDim.x){
    int p0 = tb * 16;
    __syncthreads();
    // stage 1: build normalized+ReLU h1 tile [16 edges][256 ch] in LDS (bf16)
    int c4 = lane * 4;
    #pragma unroll
    for (int jj = 0; jj < 4; ++jj){
      int le = wave + jj * 4;
      int p = p0 + le;
      unsigned short h0 = 0, h1 = 0, h2 = 0, h3 = 0;
      if (p < E){
        int g = sseg[p];
        int e = eord[p];
        int cn = ei[e], rn = ei[E + e];
        ushort4 pu = *(const ushort4*)(PQb + (size_t)cn * 512 + c4);
        ushort4 qu = *(const ushort4*)(PQb + (size_t)rn * 512 + 256 + c4);
        float4 mm = *(const float4*)(mean1 + g * 256 + c4);
        float4 rr = *(const float4*)(rstd1 + g * 256 + c4);
        h0 = f2b(fmaxf(0.f, (b2f(pu.x) + b2f(qu.x) - mm.x) * rr.x));
        h1 = f2b(fmaxf(0.f, (b2f(pu.y) + b2f(qu.y) - mm.y) * rr.y));
        h2 = f2b(fmaxf(0.f, (b2f(pu.z) + b2f(qu.z) - mm.z) * rr.z));
        h3 = f2b(fmaxf(0.f, (b2f(pu.w) + b2f(qu.w) - mm.w) * rr.w));
      }
      ushort4 hv; hv.x = h0; hv.y = h1; hv.z = h2; hv.w = h3;
      *(ushort4*)&tileA[le][c4] = hv;
    }
    __syncthreads();
    // stage 2: 16x16 MFMA strip per wave, K=256
    f32x4 acc = {0.f, 0.f, 0.f, 0.f};
    #pragma unroll
    for (int ks = 0; ks < 8; ++ks){
      ABFrag a;
      a.q = *(const uint4*)&tileA[l15][ks * 32 + quad * 8];
      acc = __builtin_amdgcn_mfma_f32_16x16x32_bf16(a.v, bk[ks].v, acc, 0, 0, 0);
    }
    #pragma unroll
    for (int r = 0; r < 4; ++r){
      int p = p0 + quad * 4 + r;
      if (p < E) y2b[(size_t)p * 64 + wave * 16 + l15] = f2b(acc[r] + bias2);
    }
  }
}

// ---------------- stats over y2 (sorted, contiguous) ----------------
__global__ void kstats2(const unsigned short* __restrict__ y2b, const int* __restrict__ sseg,
                        int E, float* __restrict__ sum2, float* __restrict__ sq2){
  int wave = threadIdx.x >> 6, lane = threadIdx.x & 63;
  int e2 = lane >> 4, c4 = (lane & 15) * 4;
  int per = (E + gridDim.x - 1) / gridDim.x;
  int i0 = blockIdx.x * per, i1 = min(E, i0 + per);
  float s0=0,s1=0,s2=0,s3=0,q0=0,q1=0,q2=0,q3=0;
  int cur = -1;
  for (int i = i0 + wave * 4 + e2; i < i1; i += 16){
    int g = sseg[i];
    if (g != cur){
      if (cur >= 0){
        atomicAdd(&sum2[cur*64+c4+0], s0); atomicAdd(&sum2[cur*64+c4+1], s1);
        atomicAdd(&sum2[cur*64+c4+2], s2); atomicAdd(&sum2[cur*64+c4+3], s3);
        atomicAdd(&sq2[cur*64+c4+0], q0); atomicAdd(&sq2[cur*64+c4+1], q1);
        atomicAdd(&sq2[cur*64+c4+2], q2); atomicAdd(&sq2[cur*64+c4+3], q3);
        s0=s1=s2=s3=q0=q1=q2=q3=0.f;
      }
      cur = g;
    }
    ushort4 yu = *(const ushort4*)(y2b + (size_t)i * 64 + c4);
    float y0 = b2f(yu.x), y1 = b2f(yu.y), y2v = b2f(yu.z), y3 = b2f(yu.w);
    s0 += y0; s1 += y1; s2 += y2v; s3 += y3;
    q0 += y0*y0; q1 += y1*y1; q2 += y2v*y2v; q3 += y3*y3;
  }
  if (cur >= 0){
    atomicAdd(&sum2[cur*64+c4+0], s0); atomicAdd(&sum2[cur*64+c4+1], s1);
    atomicAdd(&sum2[cur*64+c4+2], s2); atomicAdd(&sum2[cur*64+c4+3], s3);
    atomicAdd(&sq2[cur*64+c4+0], q0); atomicAdd(&sq2[cur*64+c4+1], q1);
    atomicAdd(&sq2[cur*64+c4+2], q2); atomicAdd(&sq2[cur*64+c4+3], q3);
  }
}

// ---------------- final: normalize+ReLU layer2 -> GEMV W3 -> scatter to orig order ----------------
__global__ void kfinal(const unsigned short* __restrict__ y2b, const int* __restrict__ eord,
                       const int* __restrict__ sseg, const float* __restrict__ mean2,
                       const float* __restrict__ rstd2, const float* __restrict__ W3,
                       const float* __restrict__ b3, float* __restrict__ out, int E){
  __shared__ float w3s[64];
  if (threadIdx.x < 64) w3s[threadIdx.x] = W3[threadIdx.x];
  __syncthreads();
  float b3v = b3[0];
  int idx = blockIdx.x * blockDim.x + threadIdx.x;
  for (int i = idx; i < E; i += gridDim.x * blockDim.x){
    int g = sseg[i];
    float acc = b3v;
    const unsigned short* yr = y2b + (size_t)i * 64;
    const float* mg = mean2 + g * 64;
    const float* rg = rstd2 + g * 64;
    #pragma unroll
    for (int c = 0; c < 64; c += 4){
      ushort4 yu = *(const ushort4*)(yr + c);
      float4 mm = *(const float4*)(mg + c);
      float4 rr = *(const float4*)(rg + c);
      acc += fmaxf(0.f, (b2f(yu.x) - mm.x) * rr.x) * w3s[c + 0];
      acc += fmaxf(0.f, (b2f(yu.y) - mm.y) * rr.y) * w3s[c + 1];
      acc += fmaxf(0.f, (b2f(yu.z) - mm.z) * rr.z) * w3s[c + 2];
      acc += fmaxf(0.f, (b2f(yu.w) - mm.w) * rr.w) * w3s[c + 3];
    }
    out[eord[i]] = acc;
  }
}

extern "C" void kernel_launch(void* const* d_in, const int* in_sizes, int n_in,
                              void* d_out, int out_size, void* d_ws, size_t ws_size,
                              hipStream_t stream){
  const float* emb  = (const float*)d_in[0];
  const int*   ei   = (const int*)d_in[1];
  const int*   batch= (const int*)d_in[2];
  const float* W1   = (const float*)d_in[3];
  const float* b1   = (const float*)d_in[4];
  const float* W2   = (const float*)d_in[5];
  const float* b2   = (const float*)d_in[6];
  const float* W3   = (const float*)d_in[7];
  const float* b3   = (const float*)d_in[8];
  int N = in_sizes[0] / 64;
  int E = in_sizes[1] / 2;
  float* out = (float*)d_out;

  char* w = (char*)d_ws;
  size_t off = 0;
  auto nxt = [&](size_t bytes) -> char* {
    char* p = w + off;
    off = (off + bytes + 255) & ~(size_t)255;
    return p;
  };
  unsigned short* embb  = (unsigned short*)nxt((size_t)N * 64 * 2);
  unsigned short* Wcatb = (unsigned short*)nxt(64 * 512 * 2);
  unsigned short* W2b   = (unsigned short*)nxt(256 * 64 * 2);
  unsigned short* PQb   = (unsigned short*)nxt((size_t)N * 512 * 2);
  unsigned short* y2b   = (unsigned short*)nxt((size_t)E * 64 * 2);
  int* eord  = (int*)nxt((size_t)E * 4);
  int* sseg  = (int*)nxt((size_t)E * 4);
  float* mean1 = (float*)nxt(NG * 256 * 4);
  float* rstd1 = (float*)nxt(NG * 256 * 4);
  float* mean2 = (float*)nxt(NG * 64 * 4);
  float* rstd2 = (float*)nxt(NG * 64 * 4);
  // zero-init region (contiguous, one memset)
  char* zbase = w + off;
  unsigned int* hist   = (unsigned int*)nxt(NG * 4);
  unsigned int* cursor = (unsigned int*)nxt(NG * 4);
  float* sum1 = (float*)nxt(NG * 256 * 4);
  float* sq1  = (float*)nxt(NG * 256 * 4);
  float* sum2 = (float*)nxt(NG * 64 * 4);
  float* sq2  = (float*)nxt(NG * 64 * 4);
  size_t zbytes = (size_t)((w + off) - zbase);
  hipMemsetAsync(zbase, 0, zbytes, stream);

  kprep<<<2048, 256, 0, stream>>>(emb, W1, W2, embb, Wcatb, W2b, N);
  khist<<<1024, 256, 0, stream>>>(ei, batch, E, hist);
  kscan<<<1, 64, 0, stream>>>(hist, cursor);
  kscatter<<<(E + 1023) / 1024, 256, 0, stream>>>(ei, batch, E, cursor, eord, sseg);
  {
    int tiles = ((N + 15) / 16) * 32;
    kgemm1<<<(tiles + 3) / 4, 256, 0, stream>>>(embb, Wcatb, b1, PQb, N);
  }
  kstats1<<<4096, 256, 0, stream>>>(PQb, ei, eord, sseg, E, sum1, sq1);
  kfin<<<(NG * 256 + 255) / 256, 256, 0, stream>>>(sum1, sq1, hist, mean1, rstd1, 256);
  kmain<<<2048, 256, 0, stream>>>(PQb, W2b, ei, eord, sseg, mean1, rstd1, b2, y2b, E);
  kstats2<<<2048, 256, 0, stream>>>(y2b, sseg, E, sum2, sq2);
  kfin<<<(NG * 64 + 255) / 256, 256, 0, stream>>>(sum2, sq2, hist, mean2, rstd2, 64);
  kfinal<<<2048, 256, 0, stream>>>(y2b, eord, sseg, mean2, rstd2, W3, b3, out, E);
}

// Round 2
// 773.917 us; speedup vs baseline: 1.2036x; 1.2036x over previous
//
#include <hip/hip_runtime.h>
#include <hip/hip_bf16.h>
#include <stdint.h>

#define NG 128
#define EPSI 1e-5f

typedef __attribute__((ext_vector_type(8))) __bf16 bf16x8;
typedef __attribute__((ext_vector_type(4))) float f32x4;

union ABFrag { bf16x8 v; unsigned short u[8]; uint4 q; };

__device__ __forceinline__ float b2f(unsigned short u){
  union { unsigned int i; float f; } v; v.i = ((unsigned int)u) << 16; return v.f;
}
__device__ __forceinline__ unsigned short f2b(float f){
  union { float f; unsigned int i; } v; v.f = f;
  unsigned int r = v.i + 0x7fffu + ((v.i >> 16) & 1u);
  return (unsigned short)(r >> 16);
}

// ---------------- prep: conversions into MFMA B-fragment order + histogram ----------------
// WcF: [tn 0..31][ks 0..1][lane 0..63][j 0..7]  value = W1cat[ks*32+quad*8+j][tn*16+l15]
//      where W1cat col n<256 -> W1[k][n] (P), n>=256 -> W1[k+64][n-256] (Q)
// W2F: [w 0..3][ks 0..7][lane][j]               value = W2[ks*32+quad*8+j][w*16+l15]
__global__ void kprep(const float* __restrict__ emb, const float* __restrict__ W1,
                      const float* __restrict__ W2,
                      const int* __restrict__ ei, const int* __restrict__ batch,
                      unsigned short* __restrict__ embb, unsigned short* __restrict__ WcF,
                      unsigned short* __restrict__ W2F, unsigned int* __restrict__ hist,
                      int N, int E){
  __shared__ unsigned int h[NG];
  for (int i = threadIdx.x; i < NG; i += 256) h[i] = 0;
  __syncthreads();
  int idx = blockIdx.x * 256 + threadIdx.x;
  int stride = gridDim.x * 256;
  int embCnt = N * 64;
  for (int i = idx; i < embCnt; i += stride) embb[i] = f2b(emb[i]);
  for (int i = idx; i < 32 * 2 * 64 * 8; i += stride){
    int j = i & 7, lane = (i >> 3) & 63, ks = (i >> 9) & 1, tn = i >> 10;
    int quad = lane >> 4, l15 = lane & 15;
    int k = ks * 32 + quad * 8 + j;
    int n = tn * 16 + l15;
    float wv = (n < 256) ? W1[k * 256 + n] : W1[(k + 64) * 256 + (n - 256)];
    WcF[i] = f2b(wv);
  }
  for (int i = idx; i < 4 * 8 * 64 * 8; i += stride){
    int j = i & 7, lane = (i >> 3) & 63, ks = (i >> 9) & 7, w = i >> 12;
    int quad = lane >> 4, l15 = lane & 15;
    W2F[i] = f2b(W2[(ks * 32 + quad * 8 + j) * 64 + w * 16 + l15]);
  }
  for (int e = idx; e < E; e += stride) atomicAdd(&h[batch[ei[e]]], 1u);
  __syncthreads();
  for (int i = threadIdx.x; i < NG; i += 256)
    if (h[i]) atomicAdd(&hist[i], h[i]);
}

__global__ void kscan(const unsigned int* __restrict__ hist, unsigned int* __restrict__ cursor){
  if (threadIdx.x == 0 && blockIdx.x == 0){
    unsigned int s = 0;
    for (int g = 0; g < NG; ++g){ cursor[g] = s; s += hist[g]; }
  }
}

// einfo[p] = {col_node, row_node, graph, orig_edge} for sorted position p
__global__ void kscatter(const int* __restrict__ ei, const int* __restrict__ batch, int E,
                         unsigned int* __restrict__ cursor, int4* __restrict__ einfo){
  __shared__ unsigned int lc[NG];
  __shared__ unsigned int base[NG];
  for (int i = threadIdx.x; i < NG; i += 256) lc[i] = 0;
  __syncthreads();
  int e0 = blockIdx.x * 1024;
  unsigned int r[4]; int gg[4], cc[4], rr[4];
  #pragma unroll
  for (int j = 0; j < 4; ++j){
    int e = e0 + j * 256 + threadIdx.x;
    if (e < E){
      int cn = ei[e], rn = ei[E + e];
      int g = batch[cn];
      cc[j] = cn; rr[j] = rn; gg[j] = g;
      r[j] = atomicAdd(&lc[g], 1u);
    }
  }
  __syncthreads();
  for (int i = threadIdx.x; i < NG; i += 256){
    unsigned int c = lc[i];
    base[i] = c ? atomicAdd(&cursor[i], c) : 0u;
  }
  __syncthreads();
  #pragma unroll
  for (int j = 0; j < 4; ++j){
    int e = e0 + j * 256 + threadIdx.x;
    if (e < E){
      unsigned int p = base[gg[j]] + r[j];
      einfo[p] = make_int4(cc[j], rr[j], gg[j], e);
    }
  }
}

// ---------------- GEMM1: PQ[N,512] = embb[N,64] @ W1cat[64,512] (+b1 on P cols) ----------------
__global__ void __launch_bounds__(256) kgemm1(const unsigned short* __restrict__ embb,
    const unsigned short* __restrict__ WcF, const float* __restrict__ b1,
    unsigned short* __restrict__ PQb, int Nn){
  int wave = threadIdx.x >> 6, lane = threadIdx.x & 63;
  int quad = lane >> 4, l15 = lane & 15;
  int t = blockIdx.x * 4 + wave;
  int tmmax = (Nn + 15) >> 4;
  int tm = t >> 5, tn = t & 31;
  if (tm >= tmmax) return;
  int m = tm * 16 + l15; if (m >= Nn) m = Nn - 1;
  f32x4 acc = {0.f, 0.f, 0.f, 0.f};
  #pragma unroll
  for (int ks = 0; ks < 2; ++ks){
    ABFrag a, b;
    a.q = *(const uint4*)(embb + (size_t)m * 64 + ks * 32 + quad * 8);
    b.q = *(const uint4*)(WcF + ((size_t)(tn * 2 + ks) * 64 + lane) * 8);
    acc = __builtin_amdgcn_mfma_f32_16x16x32_bf16(a.v, b.v, acc, 0, 0, 0);
  }
  int col = tn * 16 + l15;
  float bias = (col < 256) ? b1[col] : 0.0f;
  #pragma unroll
  for (int r = 0; r < 4; ++r){
    int rowg = tm * 16 + quad * 4 + r;
    if (rowg < Nn) PQb[(size_t)rowg * 512 + col] = f2b(acc[r] + bias);
  }
}

// ---------------- stats over y1 = P[col]+Q[row] (sorted edges, register accum, 2-unroll) -----
__global__ void kstats1(const unsigned short* __restrict__ PQb, const int4* __restrict__ einfo,
                        int E, float* __restrict__ sum1, float* __restrict__ sq1){
  int wave = threadIdx.x >> 6, lane = threadIdx.x & 63;
  int per = (E + gridDim.x - 1) / gridDim.x;
  int i0 = blockIdx.x * per;
  int i1 = min(E, i0 + per);
  int c = lane * 4;
  float s0=0,s1=0,s2=0,s3=0,q0=0,q1=0,q2=0,q3=0;
  int cur = -1;
  for (int base = i0 + wave * 2; base < i1; base += 8){
    int4 ev[2];
    ev[0] = einfo[base];
    bool v1 = (base + 1) < i1;
    ev[1] = v1 ? einfo[base + 1] : make_int4(0, 0, -1, 0);
    ushort4 pu[2], qu[2];
    #pragma unroll
    for (int k = 0; k < 2; ++k){
      pu[k] = *(const ushort4*)(PQb + (size_t)ev[k].x * 512 + c);
      qu[k] = *(const ushort4*)(PQb + (size_t)ev[k].y * 512 + 256 + c);
    }
    #pragma unroll
    for (int k = 0; k < 2; ++k){
      int g = ev[k].z;
      if (g >= 0){
        if (g != cur){
          if (cur >= 0){
            atomicAdd(&sum1[cur*256+c+0], s0); atomicAdd(&sum1[cur*256+c+1], s1);
            atomicAdd(&sum1[cur*256+c+2], s2); atomicAdd(&sum1[cur*256+c+3], s3);
            atomicAdd(&sq1[cur*256+c+0], q0); atomicAdd(&sq1[cur*256+c+1], q1);
            atomicAdd(&sq1[cur*256+c+2], q2); atomicAdd(&sq1[cur*256+c+3], q3);
            s0=s1=s2=s3=q0=q1=q2=q3=0.f;
          }
          cur = g;
        }
        float y0 = b2f(pu[k].x) + b2f(qu[k].x);
        float y1 = b2f(pu[k].y) + b2f(qu[k].y);
        float y2 = b2f(pu[k].z) + b2f(qu[k].z);
        float y3 = b2f(pu[k].w) + b2f(qu[k].w);
        s0 += y0; s1 += y1; s2 += y2; s3 += y3;
        q0 += y0*y0; q1 += y1*y1; q2 += y2*y2; q3 += y3*y3;
      }
    }
  }
  if (cur >= 0){
    atomicAdd(&sum1[cur*256+c+0], s0); atomicAdd(&sum1[cur*256+c+1], s1);
    atomicAdd(&sum1[cur*256+c+2], s2); atomicAdd(&sum1[cur*256+c+3], s3);
    atomicAdd(&sq1[cur*256+c+0], q0); atomicAdd(&sq1[cur*256+c+1], q1);
    atomicAdd(&sq1[cur*256+c+2], q2); atomicAdd(&sq1[cur*256+c+3], q3);
  }
}

__global__ void kfin(const float* __restrict__ sum, const float* __restrict__ sq,
                     const unsigned int* __restrict__ hist,
                     float* __restrict__ meanA, float* __restrict__ rstdA, int C){
  int i = blockIdx.x * blockDim.x + threadIdx.x;
  if (i >= NG * C) return;
  int g = i / C;
  float cnt = fmaxf((float)hist[g], 1.0f);
  float m = sum[i] / cnt;
  float v = sq[i] / cnt - m * m;
  meanA[i] = m;
  rstdA[i] = rsqrtf(fmaxf(v, 0.f) + EPSI);
}

// ---------------- fused: normalize+ReLU layer1 -> GEMM2 -> y2 (64-edge tiles) ----------------
__global__ void __launch_bounds__(256) kmain(const unsigned short* __restrict__ PQb,
    const unsigned short* __restrict__ W2F, const int4* __restrict__ einfo,
    const float* __restrict__ mean1, const float* __restrict__ rstd1,
    const float* __restrict__ b2, unsigned short* __restrict__ y2b, int E){
  __shared__ unsigned short tileA[64][264];  // stride 264: 2-way LDS aliasing only (free)
  int wave = threadIdx.x >> 6, lane = threadIdx.x & 63;
  int quad = lane >> 4, l15 = lane & 15;
  // W2 B-fragments for this wave's 16-col strip, coalesced from frag-ordered W2F
  ABFrag bk[8];
  #pragma unroll
  for (int ks = 0; ks < 8; ++ks)
    bk[ks].q = *(const uint4*)(W2F + ((size_t)(wave * 8 + ks) * 64 + lane) * 8);
  float bias2 = b2[wave * 16 + l15];
  int c4 = lane * 4;
  int nt = (E + 63) >> 6;
  for (int tb = blockIdx.x; tb < nt; tb += gridDim.x){
    int p0 = tb * 64;
    __syncthreads();
    if (p0 + 64 <= E){
      #pragma unroll
      for (int j = 0; j < 16; ++j){
        int le = wave * 16 + j;
        int p = p0 + le;
        int4 ev = einfo[p];
        ushort4 pu = *(const ushort4*)(PQb + (size_t)ev.x * 512 + c4);
        ushort4 qu = *(const ushort4*)(PQb + (size_t)ev.y * 512 + 256 + c4);
        float4 mm = *(const float4*)(mean1 + ev.z * 256 + c4);
        float4 rr = *(const float4*)(rstd1 + ev.z * 256 + c4);
        ushort4 hv;
        hv.x = f2b(fmaxf(0.f, (b2f(pu.x) + b2f(qu.x) - mm.x) * rr.x));
        hv.y = f2b(fmaxf(0.f, (b2f(pu.y) + b2f(qu.y) - mm.y) * rr.y));
        hv.z = f2b(fmaxf(0.f, (b2f(pu.z) + b2f(qu.z) - mm.z) * rr.z));
        hv.w = f2b(fmaxf(0.f, (b2f(pu.w) + b2f(qu.w) - mm.w) * rr.w));
        *(ushort4*)&tileA[le][c4] = hv;
      }
    } else {
      #pragma unroll
      for (int j = 0; j < 16; ++j){
        int le = wave * 16 + j;
        int p = p0 + le;
        ushort4 hv; hv.x = hv.y = hv.z = hv.w = 0;
        if (p < E){
          int4 ev = einfo[p];
          ushort4 pu = *(const ushort4*)(PQb + (size_t)ev.x * 512 + c4);
          ushort4 qu = *(const ushort4*)(PQb + (size_t)ev.y * 512 + 256 + c4);
          float4 mm = *(const float4*)(mean1 + ev.z * 256 + c4);
          float4 rr = *(const float4*)(rstd1 + ev.z * 256 + c4);
          hv.x = f2b(fmaxf(0.f, (b2f(pu.x) + b2f(qu.x) - mm.x) * rr.x));
          hv.y = f2b(fmaxf(0.f, (b2f(pu.y) + b2f(qu.y) - mm.y) * rr.y));
          hv.z = f2b(fmaxf(0.f, (b2f(pu.z) + b2f(qu.z) - mm.z) * rr.z));
          hv.w = f2b(fmaxf(0.f, (b2f(pu.w) + b2f(qu.w) - mm.w) * rr.w));
        }
        *(ushort4*)&tileA[le][c4] = hv;
      }
    }
    __syncthreads();
    f32x4 acc[4];
    #pragma unroll
    for (int eg = 0; eg < 4; ++eg){ acc[eg][0]=0.f; acc[eg][1]=0.f; acc[eg][2]=0.f; acc[eg][3]=0.f; }
    #pragma unroll
    for (int eg = 0; eg < 4; ++eg)
      #pragma unroll
      for (int ks = 0; ks < 8; ++ks){
        ABFrag a;
        a.q = *(const uint4*)&tileA[eg * 16 + l15][ks * 32 + quad * 8];
        acc[eg] = __builtin_amdgcn_mfma_f32_16x16x32_bf16(a.v, bk[ks].v, acc[eg], 0, 0, 0);
      }
    #pragma unroll
    for (int eg = 0; eg < 4; ++eg)
      #pragma unroll
      for (int r = 0; r < 4; ++r){
        int p = p0 + eg * 16 + quad * 4 + r;
        if (p < E) y2b[(size_t)p * 64 + wave * 16 + l15] = f2b(acc[eg][r] + bias2);
      }
  }
}

// ---------------- stats over y2 (sorted, contiguous) ----------------
__global__ void kstats2(const unsigned short* __restrict__ y2b, const int4* __restrict__ einfo,
                        int E, float* __restrict__ sum2, float* __restrict__ sq2){
  int wave = threadIdx.x >> 6, lane = threadIdx.x & 63;
  int e2 = lane >> 4, c4 = (lane & 15) * 4;
  int per = (E + gridDim.x - 1) / gridDim.x;
  int i0 = blockIdx.x * per, i1 = min(E, i0 + per);
  float s0=0,s1=0,s2=0,s3=0,q0=0,q1=0,q2=0,q3=0;
  int cur = -1;
  for (int i = i0 + wave * 4 + e2; i < i1; i += 16){
    int g = einfo[i].z;
    if (g != cur){
      if (cur >= 0){
        atomicAdd(&sum2[cur*64+c4+0], s0); atomicAdd(&sum2[cur*64+c4+1], s1);
        atomicAdd(&sum2[cur*64+c4+2], s2); atomicAdd(&sum2[cur*64+c4+3], s3);
        atomicAdd(&sq2[cur*64+c4+0], q0); atomicAdd(&sq2[cur*64+c4+1], q1);
        atomicAdd(&sq2[cur*64+c4+2], q2); atomicAdd(&sq2[cur*64+c4+3], q3);
        s0=s1=s2=s3=q0=q1=q2=q3=0.f;
      }
      cur = g;
    }
    ushort4 yu = *(const ushort4*)(y2b + (size_t)i * 64 + c4);
    float y0 = b2f(yu.x), y1 = b2f(yu.y), y2v = b2f(yu.z), y3 = b2f(yu.w);
    s0 += y0; s1 += y1; s2 += y2v; s3 += y3;
    q0 += y0*y0; q1 += y1*y1; q2 += y2v*y2v; q3 += y3*y3;
  }
  if (cur >= 0){
    atomicAdd(&sum2[cur*64+c4+0], s0); atomicAdd(&sum2[cur*64+c4+1], s1);
    atomicAdd(&sum2[cur*64+c4+2], s2); atomicAdd(&sum2[cur*64+c4+3], s3);
    atomicAdd(&sq2[cur*64+c4+0], q0); atomicAdd(&sq2[cur*64+c4+1], q1);
    atomicAdd(&sq2[cur*64+c4+2], q2); atomicAdd(&sq2[cur*64+c4+3], q3);
  }
}

// ---------------- final: normalize+ReLU layer2 -> GEMV W3 -> scatter to orig order ----------
__global__ void kfinal(const unsigned short* __restrict__ y2b, const int4* __restrict__ einfo,
                       const float* __restrict__ mean2, const float* __restrict__ rstd2,
                       const float* __restrict__ W3, const float* __restrict__ b3,
                       float* __restrict__ out, int E){
  __shared__ float w3s[64];
  if (threadIdx.x < 64) w3s[threadIdx.x] = W3[threadIdx.x];
  __syncthreads();
  float b3v = b3[0];
  int idx = blockIdx.x * blockDim.x + threadIdx.x;
  for (int i = idx; i < E; i += gridDim.x * blockDim.x){
    int4 ev = einfo[i];
    int g = ev.z;
    float acc = b3v;
    const unsigned short* yr = y2b + (size_t)i * 64;
    const float* mg = mean2 + g * 64;
    const float* rg = rstd2 + g * 64;
    #pragma unroll
    for (int c = 0; c < 64; c += 4){
      ushort4 yu = *(const ushort4*)(yr + c);
      float4 mm = *(const float4*)(mg + c);
      float4 rr = *(const float4*)(rg + c);
      acc += fmaxf(0.f, (b2f(yu.x) - mm.x) * rr.x) * w3s[c + 0];
      acc += fmaxf(0.f, (b2f(yu.y) - mm.y) * rr.y) * w3s[c + 1];
      acc += fmaxf(0.f, (b2f(yu.z) - mm.z) * rr.z) * w3s[c + 2];
      acc += fmaxf(0.f, (b2f(yu.w) - mm.w) * rr.w) * w3s[c + 3];
    }
    out[ev.w] = acc;
  }
}

extern "C" void kernel_launch(void* const* d_in, const int* in_sizes, int n_in,
                              void* d_out, int out_size, void* d_ws, size_t ws_size,
                              hipStream_t stream){
  const float* emb  = (const float*)d_in[0];
  const int*   ei   = (const int*)d_in[1];
  const int*   batch= (const int*)d_in[2];
  const float* W1   = (const float*)d_in[3];
  const float* b1   = (const float*)d_in[4];
  const float* W2   = (const float*)d_in[5];
  const float* b2   = (const float*)d_in[6];
  const float* W3   = (const float*)d_in[7];
  const float* b3   = (const float*)d_in[8];
  int N = in_sizes[0] / 64;
  int E = in_sizes[1] / 2;
  float* out = (float*)d_out;

  char* w = (char*)d_ws;
  size_t off = 0;
  auto nxt = [&](size_t bytes) -> char* {
    char* p = w + off;
    off = (off + bytes + 255) & ~(size_t)255;
    return p;
  };
  unsigned short* embb = (unsigned short*)nxt((size_t)N * 64 * 2);
  unsigned short* WcF  = (unsigned short*)nxt(32 * 2 * 64 * 8 * 2);
  unsigned short* W2F  = (unsigned short*)nxt(4 * 8 * 64 * 8 * 2);
  unsigned short* PQb  = (unsigned short*)nxt((size_t)N * 512 * 2);
  unsigned short* y2b  = (unsigned short*)nxt((size_t)E * 64 * 2);
  int4* einfo = (int4*)nxt((size_t)E * 16);
  float* mean1 = (float*)nxt(NG * 256 * 4);
  float* rstd1 = (float*)nxt(NG * 256 * 4);
  float* mean2 = (float*)nxt(NG * 64 * 4);
  float* rstd2 = (float*)nxt(NG * 64 * 4);
  // zero-init region (contiguous, one memset)
  char* zbase = w + off;
  unsigned int* hist   = (unsigned int*)nxt(NG * 4);
  unsigned int* cursor = (unsigned int*)nxt(NG * 4);
  float* sum1 = (float*)nxt(NG * 256 * 4);
  float* sq1  = (float*)nxt(NG * 256 * 4);
  float* sum2 = (float*)nxt(NG * 64 * 4);
  float* sq2  = (float*)nxt(NG * 64 * 4);
  size_t zbytes = (size_t)((w + off) - zbase);
  hipMemsetAsync(zbase, 0, zbytes, stream);

  kprep<<<2048, 256, 0, stream>>>(emb, W1, W2, ei, batch, embb, WcF, W2F, hist, N, E);
  kscan<<<1, 64, 0, stream>>>(hist, cursor);
  kscatter<<<(E + 1023) / 1024, 256, 0, stream>>>(ei, batch, E, cursor, einfo);
  {
    int tiles = ((N + 15) / 16) * 32;
    kgemm1<<<(tiles + 3) / 4, 256, 0, stream>>>(embb, WcF, b1, PQb, N);
  }
  kstats1<<<4096, 256, 0, stream>>>(PQb, einfo, E, sum1, sq1);
  kfin<<<(NG * 256 + 255) / 256, 256, 0, stream>>>(sum1, sq1, hist, mean1, rstd1, 256);
  kmain<<<2048, 256, 0, stream>>>(PQb, W2F, einfo, mean1, rstd1, b2, y2b, E);
  kstats2<<<2048, 256, 0, stream>>>(y2b, einfo, E, sum2, sq2);
  kfin<<<(NG * 64 + 255) / 256, 256, 0, stream>>>(sum2, sq2, hist, mean2, rstd2, 64);
  kfinal<<<2048, 256, 0, stream>>>(y2b, einfo, mean2, rstd2, W3, b3, out, E);
}